// Round 10
// baseline (156.342 us; speedup 1.0000x reference)
//
#include <hip/hip_runtime.h>
#include <hip/hip_bf16.h>

#define TGT   64
#define SRCN  64
#define BATCH 32
#define HID   512
#define ATT   512
#define MROWS (TGT * BATCH)          // 2048 rows per z
#define REP   3                      // measurement round: x3 identical body reps

typedef __bf16 bf16_t;
typedef __bf16 bf16x8 __attribute__((ext_vector_type(8)));
typedef float  f32x4  __attribute__((ext_vector_type(4)));

// HW transcendentals (round-3 lesson: libm exp2f/__frcp_rn cost 29 us).
__device__ __forceinline__ float fast_exp2(float x) {
#if __has_builtin(__builtin_amdgcn_exp2f)
  return __builtin_amdgcn_exp2f(x);
#else
  float r; asm("v_exp_f32 %0, %1\n\ts_nop 1" : "=v"(r) : "v"(x)); return r;
#endif
}
__device__ __forceinline__ float fast_rcp(float x) {
#if __has_builtin(__builtin_amdgcn_rcpf)
  return __builtin_amdgcn_rcpf(x);
#else
  float r; asm("v_rcp_f32 %0, %1\n\ts_nop 1" : "=v"(r) : "v"(x)); return r;
#endif
}

#define MFMA(a, b, c) __builtin_amdgcn_mfma_f32_16x16x32_bf16((a), (b), (c), 0, 0, 0)

// ---------------------------------------------------------------------------
// proj_gemm v2.1 (R7 body) wrapped in REP identical reps (acc reset per rep,
// identical C written each rep). Rep 1 = cold caches, reps 2-3 = warm.
// ---------------------------------------------------------------------------
__global__ __launch_bounds__(256) void proj_gemm(
    const float* __restrict__ h_t, const float* __restrict__ srcp,
    const float* __restrict__ Wa, float* __restrict__ C)
{
  const int z = blockIdx.z;
  const float* __restrict__ A = z ? srcp : h_t;
  const int mbase = blockIdx.x * 64;
  const int nbase = blockIdx.y * 64;

  __shared__ bf16_t Ah[64][72];
  __shared__ bf16_t Al[64][72];
  __shared__ bf16_t Bh[64][72];   // transposed: Bh[n][k]
  __shared__ bf16_t Bl[64][72];

  const int tid  = threadIdx.x;
  const int lane = tid & 63;
  const int wv   = tid >> 6;          // 0..3
  const int wm   = (wv & 1) * 32;
  const int wn   = (wv >> 1) * 32;
  const int l15  = lane & 15;
  const int qd   = lane >> 4;

  const int arow = tid >> 2;
  const int akc  = (tid & 3) * 16;
  const int bn = tid & 63;
  const int bkg = (tid >> 6) * 16;

  const float* Aptr = A + (size_t)(mbase + arow) * HID + akc;
  const float* Bptr = Wa + (size_t)(z * HID + bkg) * ATT + nbase + bn;

  for (int rep = 0; rep < REP; ++rep) {
    f32x4 acc00 = {0.f, 0.f, 0.f, 0.f};
    f32x4 acc01 = acc00, acc10 = acc00, acc11 = acc00;

    for (int kb = 0; kb < HID; kb += 64) {
      if (kb | rep) __syncthreads();

      float4 a0 = *(const float4*)(Aptr + kb);
      float4 a1 = *(const float4*)(Aptr + kb + 4);
      float4 a2 = *(const float4*)(Aptr + kb + 8);
      float4 a3 = *(const float4*)(Aptr + kb + 12);
      const float* bp = Bptr + (size_t)kb * ATT;
      float bv[16];
#pragma unroll
      for (int j = 0; j < 16; ++j) bv[j] = bp[(size_t)j * ATT];

      {
        float av[16] = {a0.x, a0.y, a0.z, a0.w, a1.x, a1.y, a1.z, a1.w,
                        a2.x, a2.y, a2.z, a2.w, a3.x, a3.y, a3.z, a3.w};
        bf16x8 hi0, hi1, lo0, lo1;
#pragma unroll
        for (int j = 0; j < 8; ++j) {
          bf16_t h = (bf16_t)av[j];
          hi0[j] = h;
          lo0[j] = (bf16_t)(av[j] - (float)h);
          bf16_t h2 = (bf16_t)av[j + 8];
          hi1[j] = h2;
          lo1[j] = (bf16_t)(av[j + 8] - (float)h2);
        }
        *(bf16x8*)&Ah[arow][akc]     = hi0;
        *(bf16x8*)&Ah[arow][akc + 8] = hi1;
        *(bf16x8*)&Al[arow][akc]     = lo0;
        *(bf16x8*)&Al[arow][akc + 8] = lo1;
      }
      {
        bf16x8 hi0, hi1, lo0, lo1;
#pragma unroll
        for (int j = 0; j < 8; ++j) {
          bf16_t h = (bf16_t)bv[j];
          hi0[j] = h;
          lo0[j] = (bf16_t)(bv[j] - (float)h);
          bf16_t h2 = (bf16_t)bv[j + 8];
          hi1[j] = h2;
          lo1[j] = (bf16_t)(bv[j + 8] - (float)h2);
        }
        *(bf16x8*)&Bh[bn][bkg]     = hi0;
        *(bf16x8*)&Bh[bn][bkg + 8] = hi1;
        *(bf16x8*)&Bl[bn][bkg]     = lo0;
        *(bf16x8*)&Bl[bn][bkg + 8] = lo1;
      }
      __syncthreads();

#pragma unroll
      for (int h = 0; h < 2; ++h) {
        const int kh = h * 32 + qd * 8;
        bf16x8 ah0 = *(const bf16x8*)&Ah[wm + l15][kh];
        bf16x8 ah1 = *(const bf16x8*)&Ah[wm + 16 + l15][kh];
        bf16x8 al0 = *(const bf16x8*)&Al[wm + l15][kh];
        bf16x8 al1 = *(const bf16x8*)&Al[wm + 16 + l15][kh];
        bf16x8 bh0 = *(const bf16x8*)&Bh[wn + l15][kh];
        bf16x8 bh1 = *(const bf16x8*)&Bh[wn + 16 + l15][kh];
        bf16x8 bl0 = *(const bf16x8*)&Bl[wn + l15][kh];
        bf16x8 bl1 = *(const bf16x8*)&Bl[wn + 16 + l15][kh];

        acc00 = MFMA(ah0, bh0, acc00);
        acc01 = MFMA(ah0, bh1, acc01);
        acc10 = MFMA(ah1, bh0, acc10);
        acc11 = MFMA(ah1, bh1, acc11);
        acc00 = MFMA(al0, bh0, acc00);
        acc01 = MFMA(al0, bh1, acc01);
        acc10 = MFMA(al1, bh0, acc10);
        acc11 = MFMA(al1, bh1, acc11);
        acc00 = MFMA(ah0, bl0, acc00);
        acc01 = MFMA(ah0, bl1, acc01);
        acc10 = MFMA(ah1, bl0, acc10);
        acc11 = MFMA(ah1, bl1, acc11);
      }
    }

    float* Cz = C + (size_t)z * (MROWS * ATT);
#pragma unroll
    for (int r = 0; r < 4; ++r) {
      int row0 = mbase + wm + qd * 4 + r;
      int row1 = row0 + 16;
      int col0 = nbase + wn + l15;
      Cz[(size_t)row0 * ATT + col0]      = acc00[r];
      Cz[(size_t)row0 * ATT + col0 + 16] = acc01[r];
      Cz[(size_t)row1 * ATT + col0]      = acc10[r];
      Cz[(size_t)row1 * ATT + col0 + 16] = acc11[r];
    }
  }
}

// ---------------------------------------------------------------------------
// attn_fused v4 (R7 body, the best variant) wrapped in REP identical reps.
// ---------------------------------------------------------------------------
__global__ __launch_bounds__(512) void attn_fused(
    const float* __restrict__ ws, const float* __restrict__ srcp,
    const float* __restrict__ Va, float* __restrict__ out)
{
  const float* __restrict__ h_part = ws;
  const float* __restrict__ s_part = ws + (size_t)TGT * BATCH * ATT;
  const float SC = 2.8853900817779268f;   // 2*log2(e)

  const int t0   = blockIdx.x * 4;
  const int b    = blockIdx.y;
  const int tid  = threadIdx.x;
  const int lane = tid & 63;
  const int wv   = tid >> 6;              // 0..7

  __shared__ float scoreLds[4][64];
  __shared__ float attnLds[4][64];

  const int abase = lane * 8;

  for (int rep = 0; rep < REP; ++rep) {
    if (rep) __syncthreads();

    float va[8], eH[4][8];
    *(float4*)&va[0] = *(const float4*)(Va + abase);
    *(float4*)&va[4] = *(const float4*)(Va + abase + 4);

    float vsum = 0.f;
#pragma unroll
    for (int j = 0; j < 8; ++j) vsum += va[j];
#pragma unroll
    for (int off = 32; off; off >>= 1) vsum += __shfl_xor(vsum, off);

#pragma unroll
    for (int t = 0; t < 4; ++t) {
      const float* hp = h_part + ((size_t)(t0 + t) * BATCH + b) * ATT + abase;
      float4 h0 = *(const float4*)hp;
      float4 h1 = *(const float4*)(hp + 4);
      float hv[8] = {h0.x, h0.y, h0.z, h0.w, h1.x, h1.y, h1.z, h1.w};
#pragma unroll
      for (int j = 0; j < 8; ++j) eH[t][j] = fast_exp2(hv[j] * SC);
    }

    // ---- scores: 8 s-rows per wave ----
#pragma unroll 2
    for (int i = 0; i < 8; ++i) {
      const int s = wv * 8 + i;
      const float* sp = s_part + ((size_t)s * BATCH + b) * ATT + abase;
      float4 s0 = *(const float4*)sp;
      float4 s1 = *(const float4*)(sp + 4);
      float sv[8] = {s0.x, s0.y, s0.z, s0.w, s1.x, s1.y, s1.z, s1.w};
      float ex[8];
#pragma unroll
      for (int j = 0; j < 8; ++j) ex[j] = fast_exp2(sv[j] * SC);

      float q0 = 0.f, q1 = 0.f, q2 = 0.f, q3 = 0.f;
#pragma unroll
      for (int j = 0; j < 8; ++j) {
        float e = ex[j];
        float vj = va[j];
        float y0 = fmaf(e, eH[0][j], 1.0f);
        float y1 = fmaf(e, eH[1][j], 1.0f);
        float y2 = fmaf(e, eH[2][j], 1.0f);
        float y3 = fmaf(e, eH[3][j], 1.0f);
        float r01 = fast_rcp(y0 * y1);
        float r23 = fast_rcp(y2 * y3);
        q0 = fmaf(vj * y1, r01, q0);
        q1 = fmaf(vj * y0, r01, q1);
        q2 = fmaf(vj * y3, r23, q2);
        q3 = fmaf(vj * y2, r23, q3);
      }
#pragma unroll
      for (int off = 32; off; off >>= 1) {
        q0 += __shfl_xor(q0, off);
        q1 += __shfl_xor(q1, off);
        q2 += __shfl_xor(q2, off);
        q3 += __shfl_xor(q3, off);
      }
      if (lane == 0) {
        scoreLds[0][s] = vsum - 2.0f * q0;
        scoreLds[1][s] = vsum - 2.0f * q1;
        scoreLds[2][s] = vsum - 2.0f * q2;
        scoreLds[3][s] = vsum - 2.0f * q3;
      }
    }
    __syncthreads();

    // ---- softmax over s: waves 0..3 handle t = wv, lane = s ----
    if (wv < 4) {
      float sc = scoreLds[wv][lane];
      float m = sc;
#pragma unroll
      for (int off = 32; off; off >>= 1) m = fmaxf(m, __shfl_xor(m, off));
      float e = fast_exp2((sc - m) * 1.4426950408889634f);
      float ssum = e;
#pragma unroll
      for (int off = 32; off; off >>= 1) ssum += __shfl_xor(ssum, off);
      attnLds[wv][lane] = e * fast_rcp(ssum);
    }
    __syncthreads();

    // ---- context: thread h = tid covers one of 512 hidden dims ----
    {
      float c0 = 0.f, c1 = 0.f, c2 = 0.f, c3 = 0.f;
      const float* sb = srcp + (size_t)b * HID + tid;
#pragma unroll 8
      for (int s = 0; s < SRCN; ++s) {
        float sv = sb[(size_t)s * BATCH * HID];
        c0 = fmaf(attnLds[0][s], sv, c0);
        c1 = fmaf(attnLds[1][s], sv, c1);
        c2 = fmaf(attnLds[2][s], sv, c2);
        c3 = fmaf(attnLds[3][s], sv, c3);
      }
      out[((size_t)(t0 + 0) * BATCH + b) * HID + tid] = c0;
      out[((size_t)(t0 + 1) * BATCH + b) * HID + tid] = c1;
      out[((size_t)(t0 + 2) * BATCH + b) * HID + tid] = c2;
      out[((size_t)(t0 + 3) * BATCH + b) * HID + tid] = c3;
    }
  }
}

extern "C" void kernel_launch(void* const* d_in, const int* in_sizes, int n_in,
                              void* d_out, int out_size, void* d_ws, size_t ws_size,
                              hipStream_t stream) {
  const float* h_t = (const float*)d_in[0];   // (64,32,512)
  const float* src = (const float*)d_in[1];   // (64,32,512)
  const float* Wa  = (const float*)d_in[2];   // (1024,512)
  const float* Va  = (const float*)d_in[3];   // (512,)
  float* out = (float*)d_out;                 // (64,32,512)
  float* C   = (float*)d_ws;                  // 8 MB: h_part + s_part fp32 [z][2048][512]

  proj_gemm<<<dim3(32, 8, 2), 256, 0, stream>>>(h_t, src, Wa, C);
  attn_fused<<<dim3(16, 32), 512, 0, stream>>>(C, src, Va, out);
}

// Round 11
// 98.066 us; speedup vs baseline: 1.5943x; 1.5943x over previous
//
#include <hip/hip_runtime.h>
#include <hip/hip_bf16.h>

#define TGT   64
#define SRCN  64
#define BATCH 32
#define HID   512
#define ATT   512
#define MROWS (TGT * BATCH)          // 2048 rows per z

typedef __bf16 bf16_t;
typedef __bf16 bf16x8 __attribute__((ext_vector_type(8)));
typedef float  f32x4  __attribute__((ext_vector_type(4)));

// HW transcendentals (round-3 lesson: libm exp2f/__frcp_rn cost 29 us).
__device__ __forceinline__ float fast_exp2(float x) {
#if __has_builtin(__builtin_amdgcn_exp2f)
  return __builtin_amdgcn_exp2f(x);
#else
  float r; asm("v_exp_f32 %0, %1\n\ts_nop 1" : "=v"(r) : "v"(x)); return r;
#endif
}
__device__ __forceinline__ float fast_rcp(float x) {
#if __has_builtin(__builtin_amdgcn_rcpf)
  return __builtin_amdgcn_rcpf(x);
#else
  float r; asm("v_rcp_f32 %0, %1\n\ts_nop 1" : "=v"(r) : "v"(x)); return r;
#endif
}

#define MFMA(a, b, c) __builtin_amdgcn_mfma_f32_16x16x32_bf16((a), (b), (c), 0, 0, 0)

// ---------------------------------------------------------------------------
// proj_gemm v3: body identical to R7 (proven ~12.5 us); epilogue changes:
//  - C layout [z][b][st][a]: row' = (m&31)*64 + (m>>5) so attn's per-b slice
//    (h rows t0..t0+7, s rows 0..63) is CONTIGUOUS (128 KB/b)
//  - SC = 2*log2(e) pre-folded into the store (attn skips all SC muls)
// Coalescing unchanged: per quad still 16 lanes x 64 B contiguous.
// ---------------------------------------------------------------------------
__global__ __launch_bounds__(256) void proj_gemm(
    const float* __restrict__ h_t, const float* __restrict__ srcp,
    const float* __restrict__ Wa, float* __restrict__ C)
{
  const int z = blockIdx.z;
  const float* __restrict__ A = z ? srcp : h_t;
  const int mbase = blockIdx.x * 64;
  const int nbase = blockIdx.y * 64;

  __shared__ bf16_t Ah[64][72];
  __shared__ bf16_t Al[64][72];
  __shared__ bf16_t Bh[64][72];   // transposed: Bh[n][k]
  __shared__ bf16_t Bl[64][72];

  const int tid  = threadIdx.x;
  const int lane = tid & 63;
  const int wv   = tid >> 6;          // 0..3
  const int wm   = (wv & 1) * 32;
  const int wn   = (wv >> 1) * 32;
  const int l15  = lane & 15;
  const int qd   = lane >> 4;

  const int arow = tid >> 2;
  const int akc  = (tid & 3) * 16;
  const int bn = tid & 63;
  const int bkg = (tid >> 6) * 16;

  const float* Aptr = A + (size_t)(mbase + arow) * HID + akc;
  const float* Bptr = Wa + (size_t)(z * HID + bkg) * ATT + nbase + bn;

  f32x4 acc00 = {0.f, 0.f, 0.f, 0.f};
  f32x4 acc01 = acc00, acc10 = acc00, acc11 = acc00;

  for (int kb = 0; kb < HID; kb += 64) {
    if (kb) __syncthreads();

    float4 a0 = *(const float4*)(Aptr + kb);
    float4 a1 = *(const float4*)(Aptr + kb + 4);
    float4 a2 = *(const float4*)(Aptr + kb + 8);
    float4 a3 = *(const float4*)(Aptr + kb + 12);
    const float* bp = Bptr + (size_t)kb * ATT;
    float bv[16];
#pragma unroll
    for (int j = 0; j < 16; ++j) bv[j] = bp[(size_t)j * ATT];

    {
      float av[16] = {a0.x, a0.y, a0.z, a0.w, a1.x, a1.y, a1.z, a1.w,
                      a2.x, a2.y, a2.z, a2.w, a3.x, a3.y, a3.z, a3.w};
      bf16x8 hi0, hi1, lo0, lo1;
#pragma unroll
      for (int j = 0; j < 8; ++j) {
        bf16_t h = (bf16_t)av[j];
        hi0[j] = h;
        lo0[j] = (bf16_t)(av[j] - (float)h);
        bf16_t h2 = (bf16_t)av[j + 8];
        hi1[j] = h2;
        lo1[j] = (bf16_t)(av[j + 8] - (float)h2);
      }
      *(bf16x8*)&Ah[arow][akc]     = hi0;
      *(bf16x8*)&Ah[arow][akc + 8] = hi1;
      *(bf16x8*)&Al[arow][akc]     = lo0;
      *(bf16x8*)&Al[arow][akc + 8] = lo1;
    }
    {
      bf16x8 hi0, hi1, lo0, lo1;
#pragma unroll
      for (int j = 0; j < 8; ++j) {
        bf16_t h = (bf16_t)bv[j];
        hi0[j] = h;
        lo0[j] = (bf16_t)(bv[j] - (float)h);
        bf16_t h2 = (bf16_t)bv[j + 8];
        hi1[j] = h2;
        lo1[j] = (bf16_t)(bv[j + 8] - (float)h2);
      }
      *(bf16x8*)&Bh[bn][bkg]     = hi0;
      *(bf16x8*)&Bh[bn][bkg + 8] = hi1;
      *(bf16x8*)&Bl[bn][bkg]     = lo0;
      *(bf16x8*)&Bl[bn][bkg + 8] = lo1;
    }
    __syncthreads();

#pragma unroll
    for (int h = 0; h < 2; ++h) {
      const int kh = h * 32 + qd * 8;
      bf16x8 ah0 = *(const bf16x8*)&Ah[wm + l15][kh];
      bf16x8 ah1 = *(const bf16x8*)&Ah[wm + 16 + l15][kh];
      bf16x8 al0 = *(const bf16x8*)&Al[wm + l15][kh];
      bf16x8 al1 = *(const bf16x8*)&Al[wm + 16 + l15][kh];
      bf16x8 bh0 = *(const bf16x8*)&Bh[wn + l15][kh];
      bf16x8 bh1 = *(const bf16x8*)&Bh[wn + 16 + l15][kh];
      bf16x8 bl0 = *(const bf16x8*)&Bl[wn + l15][kh];
      bf16x8 bl1 = *(const bf16x8*)&Bl[wn + 16 + l15][kh];

      acc00 = MFMA(ah0, bh0, acc00);
      acc01 = MFMA(ah0, bh1, acc01);
      acc10 = MFMA(ah1, bh0, acc10);
      acc11 = MFMA(ah1, bh1, acc11);
      acc00 = MFMA(al0, bh0, acc00);
      acc01 = MFMA(al0, bh1, acc01);
      acc10 = MFMA(al1, bh0, acc10);
      acc11 = MFMA(al1, bh1, acc11);
      acc00 = MFMA(ah0, bl0, acc00);
      acc01 = MFMA(ah0, bl1, acc01);
      acc10 = MFMA(ah1, bl0, acc10);
      acc11 = MFMA(ah1, bl1, acc11);
    }
  }

  // store to [z][b][st][a] with SC prescale
  const float SC = 2.8853900817779268f;   // 2*log2(e)
  float* Cz = C + (size_t)z * (MROWS * ATT);
#pragma unroll
  for (int r = 0; r < 4; ++r) {
    int m0 = mbase + wm + qd * 4 + r;
    int m1 = m0 + 16;
    int row0 = (m0 & 31) * 64 + (m0 >> 5);
    int row1 = (m1 & 31) * 64 + (m1 >> 5);
    int col0 = nbase + wn + l15;
    Cz[(size_t)row0 * ATT + col0]      = acc00[r] * SC;
    Cz[(size_t)row0 * ATT + col0 + 16] = acc01[r] * SC;
    Cz[(size_t)row1 * ATT + col0]      = acc10[r] * SC;
    Cz[(size_t)row1 * ATT + col0 + 16] = acc11[r] * SC;
  }
}

// ---------------------------------------------------------------------------
// attn_fused v6: t-tile 8 (s_part/src cross-block duplication x16 -> x8),
// 1024-thr blocks (16 waves; same 16 waves/CU TLP as R7-best), contiguous
// per-b C streams ([b][st][a] layout), SC pre-folded by proj.
// Wave w: s-rows w*4..w*4+3, 8 targets each. VALU/elem unchanged from R7.
// ---------------------------------------------------------------------------
__global__ __launch_bounds__(1024, 4) void attn_fused(
    const float* __restrict__ ws, const float* __restrict__ srcp,
    const float* __restrict__ Va, float* __restrict__ out)
{
  const float* __restrict__ h_part = ws;                            // [b][t][a]
  const float* __restrict__ s_part = ws + (size_t)TGT * BATCH * ATT; // [b][s][a]

  const int bid  = blockIdx.x;
  const int b    = bid & 31;          // same-b blocks 32 apart -> same XCD slot mod 8
  const int t0   = (bid >> 5) * 8;
  const int tid  = threadIdx.x;
  const int lane = tid & 63;
  const int wv   = tid >> 6;          // 0..15

  __shared__ float scoreLds[8][64];
  __shared__ float attnLds[8][64];

  const int abase = lane * 8;

  float va[8];
  *(float4*)&va[0] = *(const float4*)(Va + abase);
  *(float4*)&va[4] = *(const float4*)(Va + abase + 4);

  float vsum = 0.f;
#pragma unroll
  for (int j = 0; j < 8; ++j) vsum += va[j];
#pragma unroll
  for (int off = 32; off; off >>= 1) vsum += __shfl_xor(vsum, off);

  // eH[t][j] = exp2(SC*h) (prescaled by proj); h rows contiguous at b*64+t0+t
  float eH[8][8];
#pragma unroll
  for (int t = 0; t < 8; ++t) {
    const float* hp = h_part + ((size_t)(b * 64 + t0 + t)) * ATT + abase;
    float4 h0 = *(const float4*)hp;
    float4 h1 = *(const float4*)(hp + 4);
    float hv[8] = {h0.x, h0.y, h0.z, h0.w, h1.x, h1.y, h1.z, h1.w};
#pragma unroll
    for (int j = 0; j < 8; ++j) eH[t][j] = fast_exp2(hv[j]);
  }

  // ---- scores: 4 s-rows per wave, rolling depth-2 prefetch ----
  const int s0 = wv * 4;
  const float* spB = s_part + ((size_t)(b * 64 + s0)) * ATT + abase;
  float4 p0 = *(const float4*)spB;
  float4 p1 = *(const float4*)(spB + 4);
#pragma unroll
  for (int i = 0; i < 4; ++i) {
    float4 c0 = p0, c1 = p1;
    if (i < 3) {
      p0 = *(const float4*)(spB + (size_t)(i + 1) * ATT);
      p1 = *(const float4*)(spB + (size_t)(i + 1) * ATT + 4);
    }
    float sv[8] = {c0.x, c0.y, c0.z, c0.w, c1.x, c1.y, c1.z, c1.w};
    float ex[8];
#pragma unroll
    for (int j = 0; j < 8; ++j) ex[j] = fast_exp2(sv[j]);

    float q0 = 0.f, q1 = 0.f, q2 = 0.f, q3 = 0.f;
    float q4 = 0.f, q5 = 0.f, q6 = 0.f, q7 = 0.f;
#pragma unroll
    for (int j = 0; j < 8; ++j) {
      float e = ex[j];
      float vj = va[j];
      float y0 = fmaf(e, eH[0][j], 1.0f);
      float y1 = fmaf(e, eH[1][j], 1.0f);
      float y2 = fmaf(e, eH[2][j], 1.0f);
      float y3 = fmaf(e, eH[3][j], 1.0f);
      float y4 = fmaf(e, eH[4][j], 1.0f);
      float y5 = fmaf(e, eH[5][j], 1.0f);
      float y6 = fmaf(e, eH[6][j], 1.0f);
      float y7 = fmaf(e, eH[7][j], 1.0f);
      float r01 = fast_rcp(y0 * y1);
      float r23 = fast_rcp(y2 * y3);
      float r45 = fast_rcp(y4 * y5);
      float r67 = fast_rcp(y6 * y7);
      q0 = fmaf(vj * y1, r01, q0);
      q1 = fmaf(vj * y0, r01, q1);
      q2 = fmaf(vj * y3, r23, q2);
      q3 = fmaf(vj * y2, r23, q3);
      q4 = fmaf(vj * y5, r45, q4);
      q5 = fmaf(vj * y4, r45, q5);
      q6 = fmaf(vj * y7, r67, q6);
      q7 = fmaf(vj * y6, r67, q7);
    }
#pragma unroll
    for (int off = 32; off; off >>= 1) {
      q0 += __shfl_xor(q0, off);
      q1 += __shfl_xor(q1, off);
      q2 += __shfl_xor(q2, off);
      q3 += __shfl_xor(q3, off);
      q4 += __shfl_xor(q4, off);
      q5 += __shfl_xor(q5, off);
      q6 += __shfl_xor(q6, off);
      q7 += __shfl_xor(q7, off);
    }
    if (lane == 0) {
      const int s = s0 + i;
      scoreLds[0][s] = vsum - 2.0f * q0;
      scoreLds[1][s] = vsum - 2.0f * q1;
      scoreLds[2][s] = vsum - 2.0f * q2;
      scoreLds[3][s] = vsum - 2.0f * q3;
      scoreLds[4][s] = vsum - 2.0f * q4;
      scoreLds[5][s] = vsum - 2.0f * q5;
      scoreLds[6][s] = vsum - 2.0f * q6;
      scoreLds[7][s] = vsum - 2.0f * q7;
    }
  }
  __syncthreads();

  // ---- softmax over s: waves 0..7 handle t = wv, lane = s ----
  if (wv < 8) {
    float sc = scoreLds[wv][lane];
    float m = sc;
#pragma unroll
    for (int off = 32; off; off >>= 1) m = fmaxf(m, __shfl_xor(m, off));
    float e = fast_exp2((sc - m) * 1.4426950408889634f);
    float ssum = e;
#pragma unroll
    for (int off = 32; off; off >>= 1) ssum += __shfl_xor(ssum, off);
    attnLds[wv][lane] = e * fast_rcp(ssum);
  }
  __syncthreads();

  // ---- context: thread (tg = tid>>9, h = tid&511) covers 4 targets ----
  {
    const int h  = tid & 511;
    const int tg = tid >> 9;          // 0..1
    float c0 = 0.f, c1 = 0.f, c2 = 0.f, c3 = 0.f;
    const float* sb = srcp + (size_t)b * HID + h;
    const float* aL = &attnLds[tg * 4][0];
#pragma unroll 8
    for (int s = 0; s < SRCN; ++s) {
      float sv = sb[(size_t)s * BATCH * HID];
      c0 = fmaf(aL[0 * 64 + s], sv, c0);
      c1 = fmaf(aL[1 * 64 + s], sv, c1);
      c2 = fmaf(aL[2 * 64 + s], sv, c2);
      c3 = fmaf(aL[3 * 64 + s], sv, c3);
    }
    const int tb = t0 + tg * 4;
    out[((size_t)(tb + 0) * BATCH + b) * HID + h] = c0;
    out[((size_t)(tb + 1) * BATCH + b) * HID + h] = c1;
    out[((size_t)(tb + 2) * BATCH + b) * HID + h] = c2;
    out[((size_t)(tb + 3) * BATCH + b) * HID + h] = c3;
  }
}

extern "C" void kernel_launch(void* const* d_in, const int* in_sizes, int n_in,
                              void* d_out, int out_size, void* d_ws, size_t ws_size,
                              hipStream_t stream) {
  const float* h_t = (const float*)d_in[0];   // (64,32,512)
  const float* src = (const float*)d_in[1];   // (64,32,512)
  const float* Wa  = (const float*)d_in[2];   // (1024,512)
  const float* Va  = (const float*)d_in[3];   // (512,)
  float* out = (float*)d_out;                 // (64,32,512)
  float* C   = (float*)d_ws;                  // 8 MB: [z][b][st][a] fp32, SC-prescaled

  proj_gemm<<<dim3(32, 8, 2), 256, 0, stream>>>(h_t, src, Wa, C);
  attn_fused<<<256, 1024, 0, stream>>>(C, src, Va, out);
}